// Round 3
// baseline (1244.469 us; speedup 1.0000x reference)
//
#include <hip/hip_runtime.h>
#include <stdint.h>

typedef unsigned short u16;

#define IN_F   4096
#define OUT_F  11008
#define M_TOT  8192   /* 4*2048 */

__device__ __constant__ float NF4_TAB[16] = {
    -1.0f, -0.6961928009986877f, -0.5250730514526367f, -0.39491748809814453f,
    -0.28444138169288635f, -0.18477343022823334f, -0.09105003625154495f, 0.0f,
    0.07958029955625534f, 0.16093020141124725f, 0.24611230194568634f,
    0.33791524171829224f, 0.44070982933044434f, 0.5626170039176941f,
    0.7229568362236023f, 1.0f};

static __device__ __forceinline__ unsigned f2bf(float f) {
  unsigned u = __float_as_uint(f);
  u += 0x7fffu + ((u >> 16) & 1u);   // round-to-nearest-even
  return u >> 16;
}

// ---------------- dequant W: codes(int32)+absmax -> bf16, 8 elems/thread ----
__global__ __launch_bounds__(256) void dequant_w_kernel(
    const int* __restrict__ codes, const float* __restrict__ absmax,
    uint4* __restrict__ wout, int n8) {
  __shared__ float lut[16];
  if (threadIdx.x < 16) lut[threadIdx.x] = NF4_TAB[threadIdx.x];
  __syncthreads();
  int t = blockIdx.x * 256 + threadIdx.x;
  if (t >= n8) return;
  const int4* cp = (const int4*)codes + (size_t)t * 2;
  int4 c0 = cp[0];
  int4 c1 = cp[1];
  float am = absmax[t >> 3];          // 8 elems all inside one 64-block
  unsigned h0 = f2bf(lut[c0.x] * am) | (f2bf(lut[c0.y] * am) << 16);
  unsigned h1 = f2bf(lut[c0.z] * am) | (f2bf(lut[c0.w] * am) << 16);
  unsigned h2 = f2bf(lut[c1.x] * am) | (f2bf(lut[c1.y] * am) << 16);
  unsigned h3 = f2bf(lut[c1.z] * am) | (f2bf(lut[c1.w] * am) << 16);
  wout[t] = make_uint4(h0, h1, h2, h3);
}

// ---------------- convert x: fp32 -> bf16, 8 elems/thread -------------------
__global__ __launch_bounds__(256) void convert_x_kernel(
    const float4* __restrict__ x, uint4* __restrict__ xout, int n8) {
  int t = blockIdx.x * 256 + threadIdx.x;
  if (t >= n8) return;
  float4 a = x[(size_t)t * 2];
  float4 b = x[(size_t)t * 2 + 1];
  unsigned h0 = f2bf(a.x) | (f2bf(a.y) << 16);
  unsigned h1 = f2bf(a.z) | (f2bf(a.w) << 16);
  unsigned h2 = f2bf(b.x) | (f2bf(b.y) << 16);
  unsigned h3 = f2bf(b.z) | (f2bf(b.w) << 16);
  xout[t] = make_uint4(h0, h1, h2, h3);
}

// ---------------- 256x128 BK=32 bf16 MFMA GEMM, 2 blocks/CU -----------------
// C[M,N] = A[M,K] * B[N,K]^T.  8 waves (4M x 2N), per-wave 64x64 out (acc=64
// VGPR), dbuf LDS 48 KiB -> 2 blocks/CU (4 waves/SIMD).  Per K-tile: 8x
// ds_read_b128 + 16 MFMA + 1 barrier; vmcnt(0) drain is covered by the
// co-resident block (occupancy model).  XOR-swizzle involution for 64B rows
// (T2, rule #21), setprio (T5), bijective XCD swizzle (T1, 2752 = 8*344).
typedef __attribute__((ext_vector_type(8))) short short8;
typedef __attribute__((ext_vector_type(4))) float f32x4;

static __device__ __forceinline__ void async_copy16(const u16* g, u16* l) {
  __builtin_amdgcn_global_load_lds(
      (const __attribute__((address_space(1))) unsigned int*)g,
      (__attribute__((address_space(3))) unsigned int*)l, 16, 0, 0);
}

// Stage K-tile KT into buf BUF: A 256x32 (2 loads) + B 128x32 (1 load).
// Each load: 64 lanes x 16B = 16 rows of 64B, linear LDS dest; global col is
// pre-swizzled (slot ^ row&3) so store/read permutations form an involution.
#define STAGE(BUF, KT)                                                       \
  do {                                                                       \
    async_copy16(agp + (size_t)(KT) * 32, &lds[BUF][wave * 512]);            \
    async_copy16(agp + (size_t)(KT) * 32 + (size_t)128 * IN_F,               \
                 &lds[BUF][4096 + wave * 512]);                              \
    async_copy16(bgp + (size_t)(KT) * 32, &lds[BUF][8192 + wave * 512]);     \
  } while (0)

// One K-tile from buf BUF, staging tile TN into buf BUF^1.
#define KSTEP(BUF, TN)                                                       \
  do {                                                                       \
    short8 af[4], bf[4];                                                     \
    _Pragma("unroll") for (int i = 0; i < 4; ++i)                            \
        af[i] = *(const short8*)&lds[BUF][(wr * 64 + i * 16 + row16) * 32 +  \
                                          rsw];                              \
    _Pragma("unroll") for (int j = 0; j < 4; ++j)                            \
        bf[j] = *(const short8*)&lds[BUF][8192 +                             \
                                          (wc * 64 + j * 16 + row16) * 32 +  \
                                          rsw];                              \
    STAGE(BUF ^ 1, TN);                                                      \
    __builtin_amdgcn_s_setprio(1);                                           \
    _Pragma("unroll") for (int i = 0; i < 4; ++i)                            \
        _Pragma("unroll") for (int j = 0; j < 4; ++j)                        \
            acc[i][j] = __builtin_amdgcn_mfma_f32_16x16x32_bf16(             \
                af[i], bf[j], acc[i][j], 0, 0, 0);                           \
    __builtin_amdgcn_s_setprio(0);                                           \
    asm volatile("s_waitcnt vmcnt(0)\n\ts_barrier" ::: "memory");            \
  } while (0)

__global__ __launch_bounds__(512, 4) void gemm256x128_bt_bf16_kernel(
    const u16* __restrict__ A,   // [M_TOT, IN_F] bf16 bits
    const u16* __restrict__ B,   // [OUT_F, IN_F] bf16 bits
    float* __restrict__ C) {     // [M_TOT, OUT_F]
  constexpr int K  = IN_F;
  constexpr int N  = OUT_F;
  constexpr int NT = K / 32;                 // 128 K-tiles
  __shared__ u16 lds[2][(256 + 128) * 32];   // A:[0,8192) B:[8192,12288) = 48 KiB

  const int tid   = threadIdx.x;
  const int wave  = tid >> 6;                // 0..7
  const int lane  = tid & 63;
  const int wr    = wave >> 1;               // 0..3  (M dir, 64 rows)
  const int wc    = wave & 1;                // 0..1  (N dir, 64 cols)
  const int row16 = lane & 15;
  const int quad  = lane >> 4;
  const int rsw   = ((quad ^ (row16 & 3)) << 3);  // swizzled k-slot (elems)

  // T1: bijective XCD swizzle. nwg = 2752 = 8 * 344 (= 4 M-rows of 86 each).
  const int orig = blockIdx.x;
  const int tile = (orig & 7) * 344 + (orig >> 3);
  const int mb = tile / 86, nb = tile % 86;
  const int m0 = mb * 256, n0 = nb * 128;

  // staging: lane l covers row (l>>2) of a 16-row group, slot (l&3) (16B);
  // pre-swizzled global col = ((l&3) ^ ((l>>2)&3)) * 8 elems.
  const int srow = lane >> 2;
  const int scol = ((lane & 3) ^ (srow & 3)) << 3;
  const u16* agp = A + (size_t)(m0 + wave * 16 + srow) * K + scol;
  const u16* bgp = B + (size_t)(n0 + wave * 16 + srow) * K + scol;

  f32x4 acc[4][4] = {};

  STAGE(0, 0);
  asm volatile("s_waitcnt vmcnt(0)\n\ts_barrier" ::: "memory");

  for (int t = 0; t < NT; t += 2) {
    const int t1 = t + 1;                          // always < NT (NT even)
    const int t2 = (t + 2 < NT) ? t + 2 : NT - 1;  // clamped tail restage
    KSTEP(0, t1);
    KSTEP(1, t2);
  }

  // Epilogue: C/D layout col = lane&15, row = quad*4 + reg  [m89/m91]
#pragma unroll
  for (int i = 0; i < 4; ++i)
#pragma unroll
    for (int j = 0; j < 4; ++j)
#pragma unroll
      for (int r = 0; r < 4; ++r)
        C[(size_t)(m0 + wr * 64 + i * 16 + quad * 4 + r) * N +
          (n0 + wc * 64 + j * 16 + row16)] = acc[i][j][r];
}

// ---------------- fallback (ws too small): slow but correct -----------------
__global__ void fallback_kernel(const float* __restrict__ x,
                                const int* __restrict__ codes,
                                const float* __restrict__ absmax,
                                float* __restrict__ out) {
  __shared__ float lut[16];
  __shared__ float xs[16][17];
  __shared__ float ws[16][17];
  const int tx = threadIdx.x, ty = threadIdx.y;
  if (ty == 0 && tx < 16) lut[tx] = NF4_TAB[tx];
  __syncthreads();
  const int m  = blockIdx.y * 16 + ty;
  const int n0 = blockIdx.x * 16;
  float acc = 0.f;
  for (int k0 = 0; k0 < IN_F; k0 += 16) {
    xs[ty][tx] = x[(size_t)m * IN_F + k0 + tx];
    int idx = (n0 + ty) * IN_F + k0 + tx;
    ws[ty][tx] = lut[codes[idx]] * absmax[idx >> 6];
    __syncthreads();
#pragma unroll
    for (int kk = 0; kk < 16; ++kk) acc += xs[ty][kk] * ws[tx][kk];
    __syncthreads();
  }
  out[(size_t)m * OUT_F + n0 + tx] = acc;
}

// ---------------------------------------------------------------------------
extern "C" void kernel_launch(void* const* d_in, const int* in_sizes, int n_in,
                              void* d_out, int out_size, void* d_ws, size_t ws_size,
                              hipStream_t stream) {
  const float* x      = (const float*)d_in[0];  // [4,2048,4096] fp32
  const int*   codes  = (const int*)d_in[1];    // [11008,4096] int32 in [0,16)
  const float* absmax = (const float*)d_in[2];  // [704512] fp32
  float* out = (float*)d_out;                   // [4,2048,11008] fp32

  const size_t wBytes = (size_t)OUT_F * IN_F * 2;  // 90,177,536
  const size_t xBytes = (size_t)M_TOT * IN_F * 2;  // 67,108,864

  if (ws_size >= wBytes + xBytes) {
    u16* wq = (u16*)d_ws;
    u16* xq = (u16*)((char*)d_ws + wBytes);

    const int n8w = OUT_F * IN_F / 8;
    dequant_w_kernel<<<(n8w + 255) / 256, 256, 0, stream>>>(
        codes, absmax, (uint4*)wq, n8w);

    const int n8x = M_TOT * IN_F / 8;
    convert_x_kernel<<<(n8x + 255) / 256, 256, 0, stream>>>(
        (const float4*)x, (uint4*)xq, n8x);

    const int nwg = (M_TOT / 256) * (OUT_F / 128);  // 32 * 86 = 2752
    gemm256x128_bt_bf16_kernel<<<nwg, 512, 0, stream>>>(xq, wq, out);
  } else {
    dim3 blk(16, 16);
    dim3 grid(OUT_F / 16, M_TOT / 16);    // (688, 512)
    fallback_kernel<<<grid, blk, 0, stream>>>(x, codes, absmax, out);
  }
}

// Round 4
// 1214.667 us; speedup vs baseline: 1.0245x; 1.0245x over previous
//
#include <hip/hip_runtime.h>
#include <stdint.h>

typedef unsigned short u16;

#define IN_F   4096
#define OUT_F  11008
#define M_TOT  8192   /* 4*2048 */

__device__ __constant__ float NF4_TAB[16] = {
    -1.0f, -0.6961928009986877f, -0.5250730514526367f, -0.39491748809814453f,
    -0.28444138169288635f, -0.18477343022823334f, -0.09105003625154495f, 0.0f,
    0.07958029955625534f, 0.16093020141124725f, 0.24611230194568634f,
    0.33791524171829224f, 0.44070982933044434f, 0.5626170039176941f,
    0.7229568362236023f, 1.0f};

static __device__ __forceinline__ unsigned f2bf(float f) {
  unsigned u = __float_as_uint(f);
  u += 0x7fffu + ((u >> 16) & 1u);   // round-to-nearest-even
  return u >> 16;
}

// ---------------- dequant W: codes(int32)+absmax -> bf16, 8 elems/thread ----
__global__ __launch_bounds__(256) void dequant_w_kernel(
    const int* __restrict__ codes, const float* __restrict__ absmax,
    uint4* __restrict__ wout, int n8) {
  __shared__ float lut[16];
  if (threadIdx.x < 16) lut[threadIdx.x] = NF4_TAB[threadIdx.x];
  __syncthreads();
  int t = blockIdx.x * 256 + threadIdx.x;
  if (t >= n8) return;
  const int4* cp = (const int4*)codes + (size_t)t * 2;
  int4 c0 = cp[0];
  int4 c1 = cp[1];
  float am = absmax[t >> 3];          // 8 elems all inside one 64-block
  unsigned h0 = f2bf(lut[c0.x] * am) | (f2bf(lut[c0.y] * am) << 16);
  unsigned h1 = f2bf(lut[c0.z] * am) | (f2bf(lut[c0.w] * am) << 16);
  unsigned h2 = f2bf(lut[c1.x] * am) | (f2bf(lut[c1.y] * am) << 16);
  unsigned h3 = f2bf(lut[c1.z] * am) | (f2bf(lut[c1.w] * am) << 16);
  wout[t] = make_uint4(h0, h1, h2, h3);
}

// ---------------- convert x: fp32 -> bf16, 8 elems/thread -------------------
__global__ __launch_bounds__(256) void convert_x_kernel(
    const float4* __restrict__ x, uint4* __restrict__ xout, int n8) {
  int t = blockIdx.x * 256 + threadIdx.x;
  if (t >= n8) return;
  float4 a = x[(size_t)t * 2];
  float4 b = x[(size_t)t * 2 + 1];
  unsigned h0 = f2bf(a.x) | (f2bf(a.y) << 16);
  unsigned h1 = f2bf(a.z) | (f2bf(a.w) << 16);
  unsigned h2 = f2bf(b.x) | (f2bf(b.y) << 16);
  unsigned h3 = f2bf(b.z) | (f2bf(b.w) << 16);
  xout[t] = make_uint4(h0, h1, h2, h3);
}

// ---------------- 256x128 BK=32, 3-slot ring, 2 blocks/CU -------------------
// C[M,N] = A[M,K] * B[N,K]^T.  8 waves (4M x 2N), per-wave 64x64 (acc = 64
// AGPR, VGPR ~64 -> 128 total = 4 waves/SIMD bucket -> 2 blocks/CU).
// LDS = 3 ring slots x 24 KiB = 72 KiB.  Step t: stage tile t+2 (issued
// FIRST), ds_read tile t frags, 16 MFMA, s_waitcnt vmcnt(3) (never 0 -> tile
// t+1's loads landed, t+2's stay in flight), s_barrier.  ~2-step latency
// window per stage (T3/T4).  Swizzle involution for 64B rows keyed on
// (row>>1)&3 (2-way bank floor; the r3 (row&3) version was 4-way).  setprio
// (T5), bijective XCD swizzle (T1, 2752 = 8*344).
typedef __attribute__((ext_vector_type(8))) short short8;
typedef __attribute__((ext_vector_type(4))) float f32x4;

static __device__ __forceinline__ void async_copy16(const u16* g, u16* l) {
  __builtin_amdgcn_global_load_lds(
      (const __attribute__((address_space(1))) unsigned int*)g,
      (__attribute__((address_space(3))) unsigned int*)l, 16, 0, 0);
}

// Stage K-tile KT into ring slot LP: A 256x32 (2 loads) + B 128x32 (1 load).
// Each load: 64 lanes x 16B = 16 rows of 64B, linear LDS dest; global col is
// pre-swizzled (slot ^ (row>>1)&3) so store/read form an involution.
#define STAGE(LP, KT)                                                        \
  do {                                                                       \
    async_copy16(agp + (size_t)(KT) * 32, (LP) + wave * 512);                \
    async_copy16(agp + (size_t)(KT) * 32 + (size_t)128 * IN_F,               \
                 (LP) + 4096 + wave * 512);                                  \
    async_copy16(bgp + (size_t)(KT) * 32, (LP) + 8192 + wave * 512);         \
  } while (0)

__global__ __launch_bounds__(512, 4) void gemm256x128_bt_bf16_kernel(
    const u16* __restrict__ A,   // [M_TOT, IN_F] bf16 bits
    const u16* __restrict__ B,   // [OUT_F, IN_F] bf16 bits
    float* __restrict__ C) {     // [M_TOT, OUT_F]
  constexpr int K  = IN_F;
  constexpr int N  = OUT_F;
  constexpr int NT = K / 32;                 // 128 K-tiles
  __shared__ u16 lds[3][(256 + 128) * 32];   // 3 x 24 KiB = 72 KiB

  const int tid   = threadIdx.x;
  const int wave  = tid >> 6;                // 0..7
  const int lane  = tid & 63;
  const int wr    = wave >> 1;               // 0..3  (M dir, 64 rows)
  const int wc    = wave & 1;                // 0..1  (N dir, 64 cols)
  const int row16 = lane & 15;
  const int quad  = lane >> 4;
  const int rsw   = (quad ^ ((row16 >> 1) & 3)) << 3;  // swizzled k-slot (elems)

  // T1: bijective XCD swizzle. nwg = 2752 = 8 * 344.
  const int orig = blockIdx.x;
  const int tile = (orig & 7) * 344 + (orig >> 3);
  const int mb = tile / 86, nb = tile % 86;
  const int m0 = mb * 256, n0 = nb * 128;

  // staging: lane l covers LDS row wave*16 + (l>>2), 16B slot (l&3);
  // pre-swizzled global col = ((l&3) ^ ((l>>3)&3)) * 8 elems
  // ((l>>3)&3 == (ldsrow>>1)&3 since wave*16>>1 is 0 mod 4).
  const int srow = lane >> 2;
  const int scol = ((lane & 3) ^ ((lane >> 3) & 3)) << 3;
  const u16* agp = A + (size_t)(m0 + wave * 16 + srow) * K + scol;
  const u16* bgp = B + (size_t)(n0 + wave * 16 + srow) * K + scol;

  f32x4 acc[4][4] = {};

  u16* s0 = &lds[0][0];
  u16* s1 = &lds[1][0];
  u16* s2 = &lds[2][0];

  // prologue: tiles 0,1 into slots 0,1. Wait slot0's 3 loads (3 younger fly).
  STAGE(s0, 0);
  STAGE(s1, 1);
  asm volatile("s_waitcnt vmcnt(3)\n\ts_barrier" ::: "memory");

  for (int t = 0; t < NT; ++t) {
    const int tn = (t + 2 < NT) ? t + 2 : NT - 1;  // clamped redundant restage
    STAGE(s2, tn);                                  // issue-early (T14)
    short8 af[4], bf[4];
#pragma unroll
    for (int i = 0; i < 4; ++i)
      af[i] = *(const short8*)&s0[(wr * 64 + i * 16 + row16) * 32 + rsw];
#pragma unroll
    for (int j = 0; j < 4; ++j)
      bf[j] = *(const short8*)&s0[8192 + (wc * 64 + j * 16 + row16) * 32 + rsw];
    __builtin_amdgcn_s_setprio(1);
#pragma unroll
    for (int i = 0; i < 4; ++i)
#pragma unroll
      for (int j = 0; j < 4; ++j)
        acc[i][j] = __builtin_amdgcn_mfma_f32_16x16x32_bf16(
            af[i], bf[j], acc[i][j], 0, 0, 0);
    __builtin_amdgcn_s_setprio(0);
    // tile t+1's loads (issued last step) done; tile t+2's 3 stay in flight.
    asm volatile("s_waitcnt vmcnt(3)\n\ts_barrier" ::: "memory");
    u16* tmp = s0; s0 = s1; s1 = s2; s2 = tmp;
  }
  asm volatile("s_waitcnt vmcnt(0)" ::: "memory");  // drain dummy tail stages

  // Epilogue: C/D layout col = lane&15, row = quad*4 + reg  [m89/m91]
#pragma unroll
  for (int i = 0; i < 4; ++i)
#pragma unroll
    for (int j = 0; j < 4; ++j)
#pragma unroll
      for (int r = 0; r < 4; ++r)
        C[(size_t)(m0 + wr * 64 + i * 16 + quad * 4 + r) * N +
          (n0 + wc * 64 + j * 16 + row16)] = acc[i][j][r];
}

// ---------------- fallback (ws too small): slow but correct -----------------
__global__ void fallback_kernel(const float* __restrict__ x,
                                const int* __restrict__ codes,
                                const float* __restrict__ absmax,
                                float* __restrict__ out) {
  __shared__ float lut[16];
  __shared__ float xs[16][17];
  __shared__ float ws[16][17];
  const int tx = threadIdx.x, ty = threadIdx.y;
  if (ty == 0 && tx < 16) lut[tx] = NF4_TAB[tx];
  __syncthreads();
  const int m  = blockIdx.y * 16 + ty;
  const int n0 = blockIdx.x * 16;
  float acc = 0.f;
  for (int k0 = 0; k0 < IN_F; k0 += 16) {
    xs[ty][tx] = x[(size_t)m * IN_F + k0 + tx];
    int idx = (n0 + ty) * IN_F + k0 + tx;
    ws[ty][tx] = lut[codes[idx]] * absmax[idx >> 6];
    __syncthreads();
#pragma unroll
    for (int kk = 0; kk < 16; ++kk) acc += xs[ty][kk] * ws[tx][kk];
    __syncthreads();
  }
  out[(size_t)m * OUT_F + n0 + tx] = acc;
}

// ---------------------------------------------------------------------------
extern "C" void kernel_launch(void* const* d_in, const int* in_sizes, int n_in,
                              void* d_out, int out_size, void* d_ws, size_t ws_size,
                              hipStream_t stream) {
  const float* x      = (const float*)d_in[0];  // [4,2048,4096] fp32
  const int*   codes  = (const int*)d_in[1];    // [11008,4096] int32 in [0,16)
  const float* absmax = (const float*)d_in[2];  // [704512] fp32
  float* out = (float*)d_out;                   // [4,2048,11008] fp32

  const size_t wBytes = (size_t)OUT_F * IN_F * 2;  // 90,177,536
  const size_t xBytes = (size_t)M_TOT * IN_F * 2;  // 67,108,864

  if (ws_size >= wBytes + xBytes) {
    u16* wq = (u16*)d_ws;
    u16* xq = (u16*)((char*)d_ws + wBytes);

    const int n8w = OUT_F * IN_F / 8;
    dequant_w_kernel<<<(n8w + 255) / 256, 256, 0, stream>>>(
        codes, absmax, (uint4*)wq, n8w);

    const int n8x = M_TOT * IN_F / 8;
    convert_x_kernel<<<(n8x + 255) / 256, 256, 0, stream>>>(
        (const float4*)x, (uint4*)xq, n8x);

    const int nwg = (M_TOT / 256) * (OUT_F / 128);  // 32 * 86 = 2752
    gemm256x128_bt_bf16_kernel<<<nwg, 512, 0, stream>>>(xq, wq, out);
  } else {
    dim3 blk(16, 16);
    dim3 grid(OUT_F / 16, M_TOT / 16);    // (688, 512)
    fallback_kernel<<<grid, blk, 0, stream>>>(x, codes, absmax, out);
  }
}